// Round 8
// baseline (164.086 us; speedup 1.0000x reference)
//
#include <hip/hip_runtime.h>
#include <hip/hip_bf16.h>

// hexagdly conv2d as implicit GEMM with bf16 MFMA.
// out[b,co,h,w] = bias[co]
//   + sum_ci sum_{t=0..2} x[b,ci,h-1+t,w]   * k0[co,ci,t]
//   + (w even) sum_ci sum_{kh,kw} x[b,ci,h-1+kh,w-1+2kw] * k1[co,ci,kh,kw]
//   + (w odd)  sum_ci sum_{kh,kw} x[b,ci,h+kh,  w-1+2kw] * k1[co,ci,kh,kw]
//
// R8 = R6 + the one-line epilogue fix: orow base now includes *WW
// (R6/R7 failed ONLY because of the missing *WW — wrong row addressing).
// Structure: x-tile in LDS (XOR-swizzled bf16, ci-contiguous); weights
// pre-converted bf16 [tap][co][ci] in d_ws, loaded directly global->VGPR
// (L2-resident); zero barriers in the tap loop; direct NT scattered stores.

#define CIN  64
#define COUT 128
#define HH   256
#define WW   256
#define TH   8
#define TW   32
#define XR   10   // TH + 2 halo rows
#define XC   34   // TW + 2 halo cols

typedef __attribute__((ext_vector_type(8))) short short8;
typedef __attribute__((ext_vector_type(4))) float f32x4;

static __device__ __forceinline__ unsigned short f2bf(float v) {
    __hip_bfloat16 h = __float2bfloat16(v);
    return __builtin_bit_cast(unsigned short, h);
}

#define WTAP (COUT * CIN)   // halfwords per tap = 8192

// ---------- pre-kernel: k0/k1 -> bf16 [tap][co][ci] (linear) ----------
__global__ __launch_bounds__(512)
void prep_weights(const float* __restrict__ k0, const float* __restrict__ k1,
                  unsigned short* __restrict__ wsw)
{
    const int idx = blockIdx.x * 512 + threadIdx.x;   // 0..7167
    if (idx >= 7 * COUT * 8) return;
    const int t   = idx >> 10;         // tap 0..6
    const int co  = (idx >> 3) & 127;
    const int ci0 = (idx & 7) * 8;
    short8 wv;
    #pragma unroll
    for (int j = 0; j < 8; ++j) {
        const int ci = ci0 + j;
        float v = (t < 3) ? k0[(co * CIN + ci) * 3 + t]
                          : k1[(co * CIN + ci) * 4 + (t - 3)];
        wv[j] = (short)f2bf(v);
    }
    *(short8*)&wsw[t * WTAP + co * CIN + ci0] = wv;
}

__global__ __launch_bounds__(512, 4)
void hexconv_mfma(const float* __restrict__ x,
                  const unsigned short* __restrict__ wsw,
                  const float* __restrict__ bias,
                  float* __restrict__ out)
{
    // x tile, bf16, ci-contiguous, XOR-swizzled: elem ^= (col&7)*8
    __shared__ alignas(16) unsigned short xs[XR * XC * CIN];   // 43520 B
    __shared__ float bias_lds[COUT];

    const int tid  = threadIdx.x;
    const int lane = tid & 63;
    const int wid  = tid >> 6;       // 8 waves

    // XCD-aware swizzle: nwg = 2048 = 8 XCD x 256; each XCD gets one batch image
    const int wg = (blockIdx.x & 7) * 256 + (blockIdx.x >> 3);
    const int bx = wg & 7;            // w tile 0..7
    const int by = (wg >> 3) & 31;    // h tile 0..31
    const int b  = wg >> 8;           // batch 0..7

    const int h0 = by * TH;
    const int w0 = bx * TW;           // even

    if (tid < COUT) bias_lds[tid] = bias[tid];

    // ---------- stage x tile: fp32 -> bf16 (vectorized), ci-contiguous ----------
    {
        const float* xb = x + (size_t)b * CIN * HH * WW;
        // interior cols 1..32 (gw = w0..w0+31): float4 over 4 w, 2 ci per unit
        const int cg = tid & 7;              // col group: gw = w0 + 4*cg + k
        const int u0 = tid >> 3;             // unit: (row, ci-pair)
        #pragma unroll
        for (int it = 0; it < 5; ++it) {
            const int u   = u0 + it * 64;    // 0..319
            const int row = u >> 5;          // 0..9
            const int ci  = (u & 31) * 2;
            const int gh  = h0 - 1 + row;
            f32x4 a = (f32x4)0.0f, c = (f32x4)0.0f;
            if ((unsigned)gh < HH) {
                const float* pb = xb + ((size_t)ci * HH + gh) * WW + w0 + 4 * cg;
                a = *(const f32x4*)pb;
                c = *(const f32x4*)(pb + HH * WW);
            }
            #pragma unroll
            for (int k = 0; k < 4; ++k) {
                const int col = 4 * cg + 1 + k;
                unsigned int pk = (unsigned int)f2bf(a[k]) | ((unsigned int)f2bf(c[k]) << 16);
                const int e = ((row * XC + col) * CIN + ci) ^ ((col & 7) * 8);
                *(unsigned int*)&xs[e] = pk;
            }
        }
        // halo cols: col 0 (gw = w0-1) and col 33 (gw = w0+32)
        for (int i = tid; i < 2 * XR * CIN; i += 512) {
            const int side = (i >= XR * CIN) ? 1 : 0;
            const int rem  = i - side * XR * CIN;
            const int row  = rem >> 6;
            const int ci   = rem & 63;
            const int col  = side ? (XC - 1) : 0;
            const int gh   = h0 - 1 + row;
            const int gw   = side ? (w0 + TW) : (w0 - 1);
            float v = 0.f;
            if ((unsigned)gh < HH && (unsigned)gw < WW)
                v = xb[((size_t)ci * HH + gh) * WW + gw];
            const int e = ((row * XC + col) * CIN + ci) ^ ((col & 7) * 8);
            xs[e] = f2bf(v);
        }
    }

    __syncthreads();   // xs ready; xs is read-only from here -> no more barriers

    // ---------- compute: wave tiling ----------
    const int wm   = wid & 1;        // co block of 64
    const int wn   = wid >> 1;       // 2 h-rows of 32 cols each
    const int c15  = lane & 15;
    const int q8   = (lane >> 4) * 8;
    const int par  = lane & 1;       // parity of output column (w0 even)

    // A-fragment source: linear [tap][co][ci], per-lane base (co = wm*64 + c15)
    const unsigned short* wbase = wsw + (wm * 64 + c15) * CIN + q8;

    f32x4 acc[4][4];
    #pragma unroll
    for (int mi = 0; mi < 4; ++mi)
        #pragma unroll
        for (int ni = 0; ni < 4; ++ni)
            acc[mi][ni] = (f32x4)0.0f;

    #pragma unroll
    for (int tap = 0; tap < 7; ++tap) {
        // B-operand address parameters for this tap
        int R0, P, C0;
        if (tap < 3) { R0 = tap; P = 0; C0 = 1; }                   // vertical 3x1
        else { R0 = (tap - 3) >> 1; P = 1; C0 = ((tap - 3) & 1) * 2; } // hex 2x2
        const int colb  = c15 + C0;                 // + chalf*16 later (&7 invariant)
        const int swzB  = (colb & 7) * 8;
        const int bBase = ((wn * 2 + R0 + P * par) * XC + colb) * CIN + q8;

        const unsigned short* wt = wbase + tap * WTAP;

        #pragma unroll
        for (int ci0 = 0; ci0 < CIN; ci0 += 32) {
            short8 af[4];
            #pragma unroll
            for (int mi = 0; mi < 4; ++mi)
                af[mi] = *(const short8*)&wt[mi * 16 * CIN + ci0];   // global, L2-hot
            #pragma unroll
            for (int ni = 0; ni < 4; ++ni) {
                const int hr = ni >> 1, chalf = ni & 1;
                const int e = (bBase + hr * (XC * CIN) + chalf * (16 * CIN) + ci0) ^ swzB;
                short8 bf = *(const short8*)&xs[e];
                #pragma unroll
                for (int mi = 0; mi < 4; ++mi)
                    acc[mi][ni] = __builtin_amdgcn_mfma_f32_16x16x32_bf16(
                        af[mi], bf, acc[mi][ni], 0, 0, 0);
            }
        }
    }

    // ---------- epilogue: direct stores (64B contiguous per lane-quarter) ----------
    // C/D layout (16x16): col = lane&15, row = (lane>>4)*4 + reg
    #pragma unroll
    for (int mi = 0; mi < 4; ++mi) {
        const int cobase = wm * 64 + mi * 16 + (lane >> 4) * 4;
        #pragma unroll
        for (int r = 0; r < 4; ++r) {
            const int co = cobase + r;
            const float bv = bias_lds[co];
            float* orow = out + ((size_t)b * COUT + co) * HH * WW;   // FIXED: *WW
            #pragma unroll
            for (int ni = 0; ni < 4; ++ni) {
                const int h = h0 + wn * 2 + (ni >> 1);
                const int w = w0 + (ni & 1) * 16 + c15;
                __builtin_nontemporal_store(acc[mi][ni][r] + bv,
                                            &orow[(size_t)h * WW + w]);
            }
        }
    }
}

extern "C" void kernel_launch(void* const* d_in, const int* in_sizes, int n_in,
                              void* d_out, int out_size, void* d_ws, size_t ws_size,
                              hipStream_t stream) {
    const float* x    = (const float*)d_in[0];
    const float* k0   = (const float*)d_in[1];
    const float* k1   = (const float*)d_in[2];
    const float* bias = (const float*)d_in[3];
    float* out        = (float*)d_out;
    unsigned short* wsw = (unsigned short*)d_ws;   // 7*128*64*2 = 114688 B

    prep_weights<<<dim3(14, 1, 1), 512, 0, stream>>>(k0, k1, wsw);
    hexconv_mfma<<<dim3(2048, 1, 1), 512, 0, stream>>>(x, wsw, bias, out);
}

// Round 9
// 116.949 us; speedup vs baseline: 1.4031x; 1.4031x over previous
//
#include <hip/hip_runtime.h>
#include <hip/hip_bf16.h>

// hexagdly conv2d as implicit GEMM with bf16 MFMA.
// out[b,co,h,w] = bias[co]
//   + sum_ci sum_{t=0..2} x[b,ci,h-1+t,w]   * k0[co,ci,t]
//   + (w even) sum_ci sum_{kh,kw} x[b,ci,h-1+kh,w-1+2kw] * k1[co,ci,kh,kw]
//   + (w odd)  sum_ci sum_{kh,kw} x[b,ci,h+kh,  w-1+2kw] * k1[co,ci,kh,kw]
//
// R9 = R5 (98.4us, passing) with ONLY the epilogue changed: direct PLAIN
// scattered stores (4x64B contiguous segments per wave-store; cached stores
// write-combine exactly — R1 evidence; NT stores amplified 10% — R8 evidence).
// Addressing verified after the R6/R7 *WW bug hunt.

#define CIN  64
#define COUT 128
#define HH   256
#define WW   256
#define TH   8
#define TW   32
#define XR   10   // TH + 2 halo rows
#define XC   34   // TW + 2 halo cols

typedef __attribute__((ext_vector_type(8))) short short8;
typedef __attribute__((ext_vector_type(4))) float f32x4;

static __device__ __forceinline__ unsigned short f2bf(float v) {
    __hip_bfloat16 h = __float2bfloat16(v);
    return __builtin_bit_cast(unsigned short, h);
}

typedef __attribute__((address_space(1))) const unsigned int asg_u32;
typedef __attribute__((address_space(3))) unsigned int asl_u32;
static __device__ __forceinline__ void gl2lds16(const void* g, void* l) {
    __builtin_amdgcn_global_load_lds((asg_u32*)g, (asl_u32*)l, 16, 0, 0);
}

#define XS_BYTES   (XR * XC * CIN * 2)               // 43520
#define WTB_OFF    XS_BYTES
#define SMEM_BYTES (XS_BYTES + 2 * COUT * CIN * 2)   // 43520 + 32768 = 76288
#define WTAP       (COUT * CIN)                      // halfwords per tap = 8192

// ---------- pre-kernel: k0/k1 -> bf16 [tap][co][ci], pre-swizzled ----------
__global__ __launch_bounds__(512)
void prep_weights(const float* __restrict__ k0, const float* __restrict__ k1,
                  unsigned short* __restrict__ wsw)
{
    const int idx = blockIdx.x * 512 + threadIdx.x;   // 0..7167
    if (idx >= 7 * COUT * 8) return;
    const int t   = idx >> 10;         // tap 0..6
    const int co  = (idx >> 3) & 127;
    const int ci0 = (idx & 7) * 8;
    short8 wv;
    #pragma unroll
    for (int j = 0; j < 8; ++j) {
        const int ci = ci0 + j;
        float v = (t < 3) ? k0[(co * CIN + ci) * 3 + t]
                          : k1[(co * CIN + ci) * 4 + (t - 3)];
        wv[j] = (short)f2bf(v);
    }
    const int e = (co * CIN + ci0) ^ ((co & 7) * 8);
    *(short8*)&wsw[t * WTAP + e] = wv;
}

__global__ __launch_bounds__(512, 4)
void hexconv_mfma(const float* __restrict__ x,
                  const unsigned short* __restrict__ wsw,
                  const float* __restrict__ bias,
                  float* __restrict__ out)
{
    __shared__ alignas(16) char smem[SMEM_BYTES];
    __shared__ float bias_lds[COUT];
    unsigned short* xs  = (unsigned short*)smem;
    unsigned short* wtb = (unsigned short*)(smem + WTB_OFF);

    const int tid  = threadIdx.x;
    const int lane = tid & 63;
    const int wid  = tid >> 6;       // 8 waves

    // XCD-aware swizzle: nwg = 2048 = 8 XCD x 256; each XCD gets one batch image
    const int wg = (blockIdx.x & 7) * 256 + (blockIdx.x >> 3);
    const int bx = wg & 7;            // w tile 0..7
    const int by = (wg >> 3) & 31;    // h tile 0..31
    const int b  = wg >> 8;           // batch 0..7

    const int h0 = by * TH;
    const int w0 = bx * TW;           // even

    // ---- weight staging via async global->LDS (linear dest, pre-swizzled src) ----
    // wave wid owns halfwords [wid*1024, wid*1024+1024) of the 8192-halfword tap
    auto stage_tap = [&](int t, int buf) {
        const unsigned short* s0 = wsw + t * WTAP + wid * 1024;
        unsigned short* d0 = wtb + buf * WTAP + wid * 1024;
        gl2lds16(s0 + lane * 8, d0);
        gl2lds16(s0 + 512 + lane * 8, d0 + 512);
    };

    stage_tap(0, 0);   // tap 0 -> buffer 0, overlaps x staging

    if (tid < COUT) bias_lds[tid] = bias[tid];

    // ---------- stage x tile: fp32 -> bf16 (vectorized), ci-contiguous ----------
    {
        const float* xb = x + (size_t)b * CIN * HH * WW;
        // interior cols 1..32 (gw = w0..w0+31): float4 over 4 w, 2 ci per unit
        const int cg = tid & 7;              // col group: gw = w0 + 4*cg + k
        const int u0 = tid >> 3;             // unit: (row, ci-pair)
        #pragma unroll
        for (int it = 0; it < 5; ++it) {
            const int u   = u0 + it * 64;    // 0..319
            const int row = u >> 5;          // 0..9
            const int ci  = (u & 31) * 2;
            const int gh  = h0 - 1 + row;
            f32x4 a = (f32x4)0.0f, c = (f32x4)0.0f;
            if ((unsigned)gh < HH) {
                const float* pb = xb + ((size_t)ci * HH + gh) * WW + w0 + 4 * cg;
                a = *(const f32x4*)pb;
                c = *(const f32x4*)(pb + HH * WW);
            }
            #pragma unroll
            for (int k = 0; k < 4; ++k) {
                const int col = 4 * cg + 1 + k;
                unsigned int pk = (unsigned int)f2bf(a[k]) | ((unsigned int)f2bf(c[k]) << 16);
                const int e = ((row * XC + col) * CIN + ci) ^ ((col & 7) * 8);
                *(unsigned int*)&xs[e] = pk;
            }
        }
        // halo cols: col 0 (gw = w0-1) and col 33 (gw = w0+32)
        for (int i = tid; i < 2 * XR * CIN; i += 512) {
            const int side = (i >= XR * CIN) ? 1 : 0;
            const int rem  = i - side * XR * CIN;
            const int row  = rem >> 6;
            const int ci   = rem & 63;
            const int col  = side ? (XC - 1) : 0;
            const int gh   = h0 - 1 + row;
            const int gw   = side ? (w0 + TW) : (w0 - 1);
            float v = 0.f;
            if ((unsigned)gh < HH && (unsigned)gw < WW)
                v = xb[((size_t)ci * HH + gh) * WW + gw];
            const int e = ((row * XC + col) * CIN + ci) ^ ((col & 7) * 8);
            xs[e] = f2bf(v);
        }
    }

    __syncthreads();   // full drain: tap-0 weights + x tile ready

    // ---------- compute: wave tiling ----------
    const int wm   = wid & 1;        // co block of 64
    const int wn   = wid >> 1;       // 2 h-rows of 32 cols each
    const int c15  = lane & 15;
    const int q8   = (lane >> 4) * 8;
    const int par  = lane & 1;       // parity of output column (w0 even)

    const int aBase = (wm * 64 + c15) * CIN + q8;
    const int swzA  = (c15 & 7) * 8;

    f32x4 acc[4][4];
    #pragma unroll
    for (int mi = 0; mi < 4; ++mi)
        #pragma unroll
        for (int ni = 0; ni < 4; ++ni)
            acc[mi][ni] = (f32x4)0.0f;

    #pragma unroll
    for (int tap = 0; tap < 7; ++tap) {
        // issue next tap's weight loads; they stay in flight under this tap's MFMAs
        if (tap < 6) {
            stage_tap(tap + 1, (tap + 1) & 1);
            asm volatile("s_waitcnt vmcnt(2)" ::: "memory");   // tap t's loads landed
        } else {
            asm volatile("s_waitcnt vmcnt(0)" ::: "memory");
        }
        __builtin_amdgcn_s_barrier();          // all waves' tap-t weights visible
        __builtin_amdgcn_sched_barrier(0);

        const unsigned short* wc = wtb + (tap & 1) * WTAP;

        // B-operand address parameters for this tap
        int R0, P, C0;
        if (tap < 3) { R0 = tap; P = 0; C0 = 1; }                   // vertical 3x1
        else { R0 = (tap - 3) >> 1; P = 1; C0 = ((tap - 3) & 1) * 2; } // hex 2x2
        const int colb  = c15 + C0;                 // + chalf*16 later (&7 invariant)
        const int swzB  = (colb & 7) * 8;
        const int bBase = ((wn * 2 + R0 + P * par) * XC + colb) * CIN + q8;

        #pragma unroll
        for (int ci0 = 0; ci0 < CIN; ci0 += 32) {
            short8 af[4];
            #pragma unroll
            for (int mi = 0; mi < 4; ++mi)
                af[mi] = *(const short8*)&wc[(aBase + mi * 16 * CIN + ci0) ^ swzA];
            #pragma unroll
            for (int ni = 0; ni < 4; ++ni) {
                const int hr = ni >> 1, chalf = ni & 1;
                const int e = (bBase + hr * (XC * CIN) + chalf * (16 * CIN) + ci0) ^ swzB;
                short8 bf = *(const short8*)&xs[e];
                #pragma unroll
                for (int mi = 0; mi < 4; ++mi)
                    acc[mi][ni] = __builtin_amdgcn_mfma_f32_16x16x32_bf16(
                        af[mi], bf, acc[mi][ni], 0, 0, 0);
            }
        }

        // all our ds_reads done -> safe for others to overwrite buffers next iter
        asm volatile("s_waitcnt lgkmcnt(0)" ::: "memory");
        __builtin_amdgcn_sched_barrier(0);
        __builtin_amdgcn_s_barrier();
    }

    // ---------- epilogue: direct plain stores (4x64B segments per wave-store) ----------
    // C/D layout (16x16): col = lane&15, row = (lane>>4)*4 + reg
    #pragma unroll
    for (int mi = 0; mi < 4; ++mi) {
        const int cobase = wm * 64 + mi * 16 + (lane >> 4) * 4;
        #pragma unroll
        for (int r = 0; r < 4; ++r) {
            const int co = cobase + r;
            const float bv = bias_lds[co];
            float* orow = out + ((size_t)b * COUT + co) * HH * WW;
            #pragma unroll
            for (int ni = 0; ni < 4; ++ni) {
                const int h = h0 + wn * 2 + (ni >> 1);
                const int w = w0 + (ni & 1) * 16 + c15;
                orow[(size_t)h * WW + w] = acc[mi][ni][r] + bv;
            }
        }
    }
}

extern "C" void kernel_launch(void* const* d_in, const int* in_sizes, int n_in,
                              void* d_out, int out_size, void* d_ws, size_t ws_size,
                              hipStream_t stream) {
    const float* x    = (const float*)d_in[0];
    const float* k0   = (const float*)d_in[1];
    const float* k1   = (const float*)d_in[2];
    const float* bias = (const float*)d_in[3];
    float* out        = (float*)d_out;
    unsigned short* wsw = (unsigned short*)d_ws;   // 7*128*64*2 = 114688 B

    prep_weights<<<dim3(14, 1, 1), 512, 0, stream>>>(k0, k1, wsw);
    hexconv_mfma<<<dim3(2048, 1, 1), 512, 0, stream>>>(x, wsw, bias, out);
}